// Round 15
// baseline (281.442 us; speedup 1.0000x reference)
//
#include <hip/hip_runtime.h>
#include <hip/hip_bf16.h>

#define NN 100000
#define EE 1600000
#define SLAB 64            // fixed slab per node
#define KB 391             // buckets of 256 nodes: (NN+255)>>8
#define CHUNK 4096         // edges per block in scatter
#define BSLAB 4736         // per-bucket edge slab: 4096 mean + 10 sigma

static constexpr float EPSV = 1e-5f;
static constexpr float SLOPE = 0.2f;

__device__ __forceinline__ float lrelu(float v) { return v > 0.f ? v : SLOPE * v; }

__device__ __forceinline__ unsigned rne_bf16(float v) {
    unsigned u = __float_as_uint(v);
    return (u + 0x7fffu + ((u >> 16) & 1u)) >> 16;
}
__device__ __forceinline__ float bf16_lo(unsigned u) { return __uint_as_float(u << 16); }
__device__ __forceinline__ float bf16_hi(unsigned u) { return __uint_as_float(u & 0xffff0000u); }

// ---------------- CSR build (fixed bucket slabs) ----------------

__global__ void k_z(int* __restrict__ bcnt, unsigned* __restrict__ hsp,
                    unsigned* __restrict__ g1p, unsigned* __restrict__ g2p,
                    float2* __restrict__ als) {
    int i = threadIdx.x;
    if (i < KB) bcnt[i] = 0;
    if (i < 16) hsp[(size_t)NN * 16 + i] = 0u;   // sentinel zero rows
    if (i < 32) g1p[(size_t)NN * 32 + i] = 0u;
    if (i < 16) g2p[(size_t)NN * 16 + i] = 0u;
    if (i == 0) als[NN] = make_float2(-1e30f, -1e30f);  // sentinel: w -> 0
}

__global__ __launch_bounds__(256) void k_scat(const int* __restrict__ src, const int* __restrict__ dst,
                                              int* __restrict__ bcnt, unsigned int* __restrict__ ebuf) {
    __shared__ int hc[KB], hb[KB];
    int tid = threadIdx.x;
    for (int i = tid; i < KB; i += 256) hc[i] = 0;
    __syncthreads();
    int e0 = blockIdx.x * CHUNK;
    #pragma unroll
    for (int r = 0; r < CHUNK / 256; ++r) {
        int e = e0 + r * 256 + tid;
        if (e < EE) atomicAdd(&hc[dst[e] >> 8], 1);
    }
    __syncthreads();
    for (int i = tid; i < KB; i += 256) {
        int c = hc[i];
        if (c) hb[i] = atomicAdd(&bcnt[i], c);
        hc[i] = 0;
    }
    __syncthreads();
    #pragma unroll
    for (int r = 0; r < CHUNK / 256; ++r) {
        int e = e0 + r * 256 + tid;
        if (e < EE) {
            int d = dst[e];
            int b = d >> 8;
            int rk = atomicAdd(&hc[b], 1);
            ebuf[(size_t)b * BSLAB + hb[b] + rk] = ((unsigned)src[e] << 8) | (unsigned)(d & 255);
        }
    }
}

// bucket demux + fused deg/dinv/self-loop/sentinel-pad
__global__ __launch_bounds__(256) void k_bucket(const unsigned int* __restrict__ ebuf,
                                                const int* __restrict__ bcnt,
                                                int* __restrict__ col, int* __restrict__ cnt,
                                                float* __restrict__ dinv) {
    __shared__ int lc[256];
    int tid = threadIdx.x;
    int b = blockIdx.x;
    lc[tid] = 0;
    __syncthreads();
    size_t s = (size_t)b * BSLAB;
    int nb = bcnt[b];
    for (int i = tid; i < nb; i += 256) {
        unsigned v = ebuf[s + i];
        int l = v & 255;
        int r = atomicAdd(&lc[l], 1);
        col[(((b << 8) + l) << 6) + r] = v >> 8;
    }
    __syncthreads();
    int node = (b << 8) + tid;
    if (node < NN) {
        int c = lc[tid];
        cnt[node] = c;
        dinv[node] = rsqrtf((float)(c + 1));
        col[node * SLAB + c] = node;                       // self loop
        for (int j = c + 1; j < 32; ++j) col[node * SLAB + j] = NN;  // sentinel pad
    }
}

// ---------------- GEMM1: hs(pairs) = bf16((x @ W) * dinv[n]) ----------------

__global__ __launch_bounds__(256) void k_gemm1(const float* __restrict__ x,
                                               const float* __restrict__ W,
                                               const float* __restrict__ dinv,
                                               unsigned* __restrict__ hsp) {
    __shared__ float xs[64][128];               // 32 KB
    int tid = threadIdx.x;
    int lane = tid & 63;
    int wv = tid >> 6;
    int khalf = lane >> 5, f = lane & 31;
    float wreg[64];
    const float* wp = W + (khalf * 64) * 32 + f;
    #pragma unroll
    for (int i = 0; i < 64; ++i) wreg[i] = wp[i * 32];
    int n0 = blockIdx.x * 64;
    for (int i = tid; i < 64 * 32; i += 256) {
        int row = i >> 5, c4 = i & 31;
        int n = n0 + row;
        float4 v = (n < NN) ? *(const float4*)&x[(size_t)n * 128 + c4 * 4]
                            : make_float4(0.f, 0.f, 0.f, 0.f);
        *(float4*)&xs[row][c4 * 4] = v;
    }
    __syncthreads();
    #pragma unroll 4
    for (int t = 0; t < 16; ++t) {
        int row = wv * 16 + t;
        int n = n0 + row;
        if (n >= NN) break;
        const float* xp = &xs[row][khalf * 64];
        float a0 = 0.f, a1 = 0.f, a2 = 0.f, a3 = 0.f;
        #pragma unroll
        for (int j = 0; j < 16; j += 4) {
            float4 v0 = *(const float4*)&xp[(j + 0) * 4];
            float4 v1 = *(const float4*)&xp[(j + 1) * 4];
            float4 v2 = *(const float4*)&xp[(j + 2) * 4];
            float4 v3 = *(const float4*)&xp[(j + 3) * 4];
            a0 += v0.x * wreg[j * 4 + 0]  + v0.y * wreg[j * 4 + 1]  + v0.z * wreg[j * 4 + 2]  + v0.w * wreg[j * 4 + 3];
            a1 += v1.x * wreg[j * 4 + 4]  + v1.y * wreg[j * 4 + 5]  + v1.z * wreg[j * 4 + 6]  + v1.w * wreg[j * 4 + 7];
            a2 += v2.x * wreg[j * 4 + 8]  + v2.y * wreg[j * 4 + 9]  + v2.z * wreg[j * 4 + 10] + v2.w * wreg[j * 4 + 11];
            a3 += v3.x * wreg[j * 4 + 12] + v3.y * wreg[j * 4 + 13] + v3.z * wreg[j * 4 + 14] + v3.w * wreg[j * 4 + 15];
        }
        float tot = (a0 + a1) + (a2 + a3);
        tot += __shfl_xor(tot, 32);
        unsigned r16 = rne_bf16(tot * dinv[n]);
        unsigned hi16 = __shfl(r16, f + 1, 32);
        if (khalf == 0 && !(f & 1))
            hsp[n * 16 + (f >> 1)] = (hi16 << 16) | (r16 & 0xffffu);
    }
}

// generic (dn>32) masked pair-gather sum -> per-feat acc
__device__ __forceinline__ float gen_sum_hsp(const unsigned* hsp, const int* col, int base,
                                             int dn, int lane) {
    int half = lane >> 4, l16 = lane & 15;
    int c0 = col[base + lane];
    int c1 = col[base + 32 + lane];
    float aL0 = 0.f, aH0 = 0.f, aL1 = 0.f, aH1 = 0.f;
    for (int j2 = 0; j2 < dn; j2 += 4) {
        int eA = j2 + half, eB = j2 + 2 + half;
        int cA = __shfl((j2 < 32) ? c0 : c1, eA & 31, 32);
        int cB = __shfl((j2 + 2 < 32) ? c0 : c1, eB & 31, 32);
        cA = (eA < dn) ? cA : (int)NN;
        cB = (eB < dn) ? cB : (int)NN;
        unsigned uA = hsp[(size_t)cA * 16 + l16];
        unsigned uB = hsp[(size_t)cB * 16 + l16];
        aL0 += bf16_lo(uA); aH0 += bf16_hi(uA);
        aL1 += bf16_lo(uB); aH1 += bf16_hi(uB);
    }
    float accLo = aL0 + aL1, accHi = aH0 + aH1;
    accLo += __shfl_xor(accLo, 16);
    accHi += __shfl_xor(accHi, 16);
    float vLo = __shfl(accLo, lane >> 1, 32);
    float vHi = __shfl(accHi, lane >> 1, 32);
    return (lane & 1) ? vHi : vLo;
}

// ---------------- epilogue helpers (scalar args only: no scratch risk) ----------------

__device__ __forceinline__ void gat1_epilogue(
    float acc, int n, int lane,
    const float* __restrict__ dinv, const float* __restrict__ gb,
    const float* __restrict__ bng, const float* __restrict__ bnb,
    const float* __restrict__ bnm, const float* __restrict__ bnv,
    const float (*wAs)[32], const float (*wBs)[32],
    const float* __restrict__ as_, const float* __restrict__ ad_,
    unsigned* __restrict__ gp, float2* __restrict__ als, float2* __restrict__ ald) {
    float v = dinv[n] * acc + gb[lane];
    v = (v - bnm[lane]) * rsqrtf(bnv[lane] + EPSV) * bng[lane] + bnb[lane];
    v = fmaxf(v, 0.f);                           // t1[n][lane]
    float gA0 = 0.f, gA1 = 0.f, gB0 = 0.f, gB1 = 0.f;
    #pragma unroll
    for (int k = 0; k < 32; k += 2) {
        float t0 = __shfl(v, k, 32);
        float t1v = __shfl(v, k + 1, 32);
        gA0 += t0 * wAs[k][lane];     gB0 += t0 * wBs[k][lane];
        gA1 += t1v * wAs[k + 1][lane]; gB1 += t1v * wBs[k + 1][lane];
    }
    float gA = gA0 + gA1, gB = gB0 + gB1;
    float pas0 = gA * as_[lane],      pad0 = gA * ad_[lane];
    float pas1 = gB * as_[32 + lane], pad1 = gB * ad_[32 + lane];
    #pragma unroll
    for (int off = 16; off; off >>= 1) {
        pas0 += __shfl_xor(pas0, off);
        pad0 += __shfl_xor(pad0, off);
        pas1 += __shfl_xor(pas1, off);
        pad1 += __shfl_xor(pad1, off);
    }
    if (lane == 0) { als[n] = make_float2(pas0, pas1); ald[n] = make_float2(pad0, pad1); }
    gp[n * 32 + lane] = (rne_bf16(gB) << 16) | rne_bf16(gA);
}

__device__ __forceinline__ void gat2t_epilogue(
    float acc, int n, int lane,
    const float* __restrict__ dinv, const float* __restrict__ gb,
    const float* __restrict__ bng, const float* __restrict__ bnb,
    const float* __restrict__ bnm, const float* __restrict__ bnv,
    const float (*wgs)[32],
    const float* __restrict__ as_, const float* __restrict__ ad_,
    unsigned* __restrict__ g2p, float2* __restrict__ als, float2* __restrict__ ald) {
    float v = dinv[n] * acc + gb[lane];
    v = (v - bnm[lane]) * rsqrtf(bnv[lane] + EPSV) * bng[lane] + bnb[lane];
    v = fmaxf(v, 0.f);                           // t2[n][lane]
    float g0 = 0.f, g1 = 0.f;
    #pragma unroll
    for (int k = 0; k < 32; k += 2) {
        g0 += __shfl(v, k, 32) * wgs[k][lane];
        g1 += __shfl(v, k + 1, 32) * wgs[k + 1][lane];
    }
    float g = g0 + g1;
    int hh = lane >> 4, ff = lane & 15;
    float as_v = g * as_[hh * 16 + ff];
    float ad_v = g * ad_[hh * 16 + ff];
    #pragma unroll
    for (int off = 8; off; off >>= 1) {
        as_v += __shfl_xor(as_v, off);
        ad_v += __shfl_xor(ad_v, off);
    }
    float s1v = __shfl(as_v, 16, 32);
    float d1v = __shfl(ad_v, 16, 32);
    if (lane == 0) {
        als[n] = make_float2(as_v, s1v);
        ald[n] = make_float2(ad_v, d1v);
    }
    unsigned r16 = rne_bf16(g);
    unsigned hi16 = __shfl(r16, lane + 1, 32);
    if (!(lane & 1)) g2p[n * 16 + (lane >> 1)] = (hi16 << 16) | (r16 & 0xffffu);
}

__device__ __forceinline__ void gat2_out(float acc, float ws0, float ws1, int n, int lane,
                                         const float* __restrict__ b, float* __restrict__ out) {
    int hh = lane >> 4, ff = lane & 15;
    acc /= (hh ? ws1 : ws0);
    float v = 0.5f * (acc + __shfl_xor(acc, 16)) + b[ff];
    float mx = v;
    #pragma unroll
    for (int off = 8; off; off >>= 1) mx = fmaxf(mx, __shfl_xor(mx, off));
    float se = __expf(v - mx);
    #pragma unroll
    for (int off = 8; off; off >>= 1) se += __shfl_xor(se, off);
    if (hh == 0) out[(size_t)n * 16 + ff] = v - mx - __logf(se);
}

// gat2 generic (dn>32) one-pass weighted gather
__device__ __forceinline__ void gat2_gen(
    const unsigned* __restrict__ g2p, const float2* __restrict__ als, float2 ad,
    const int* __restrict__ col, int base, int dn, int lane,
    float& accO, float& ws0O, float& ws1O) {
    int c0 = col[base + lane];
    int c1 = col[base + 32 + lane];
    int half = lane >> 4, l16 = lane & 15;
    bool head1g = (l16 & 8) != 0;
    float aL0 = 0.f, aH0 = 0.f, aL1 = 0.f, aH1 = 0.f;
    float w0s = 0.f, w1s = 0.f;
    for (int j2 = 0; j2 < dn; j2 += 4) {
        int eA = j2 + half, eB = j2 + 2 + half;
        int cA = __shfl((j2 < 32) ? c0 : c1, eA & 31, 32);
        int cB = __shfl((j2 + 2 < 32) ? c0 : c1, eB & 31, 32);
        cA = (eA < dn) ? cA : (int)NN;
        cB = (eB < dn) ? cB : (int)NN;
        unsigned uA = g2p[(size_t)cA * 16 + l16];
        unsigned uB = g2p[(size_t)cB * 16 + l16];
        float2 sA = als[cA], sB = als[cB];
        float wA0 = __expf(lrelu(sA.x + ad.x)), wA1 = __expf(lrelu(sA.y + ad.y));
        float wB0 = __expf(lrelu(sB.x + ad.x)), wB1 = __expf(lrelu(sB.y + ad.y));
        float wa = head1g ? wA1 : wA0;
        float wb = head1g ? wB1 : wB0;
        aL0 += wa * bf16_lo(uA); aH0 += wa * bf16_hi(uA);
        aL1 += wb * bf16_lo(uB); aH1 += wb * bf16_hi(uB);
        w0s += wA0 + wB0; w1s += wA1 + wB1;
    }
    float accLo = aL0 + aL1, accHi = aH0 + aH1;
    accLo += __shfl_xor(accLo, 16);
    accHi += __shfl_xor(accHi, 16);
    w0s += __shfl_xor(w0s, 16);
    w1s += __shfl_xor(w1s, 16);
    float vLo = __shfl(accLo, lane >> 1, 32);
    float vHi = __shfl(accHi, lane >> 1, 32);
    accO = (lane & 1) ? vHi : vLo;
    ws0O = w0s; ws1O = w1s;
}

// ---------------- GCN1 agg (2 nodes/half-wave, 32 loads in flight) + BN + ReLU + GAT1 transform ----------------

__global__ __launch_bounds__(256, 4) void k_gcn1_gat1t(
    const unsigned* __restrict__ hsp, const int* __restrict__ cnt,
    const int* __restrict__ col, const float* __restrict__ dinv,
    const float* __restrict__ gb, const float* __restrict__ bng,
    const float* __restrict__ bnb, const float* __restrict__ bnm,
    const float* __restrict__ bnv,
    const float* __restrict__ W1, const float* __restrict__ as_, const float* __restrict__ ad_,
    unsigned* __restrict__ gp, float2* __restrict__ als, float2* __restrict__ ald) {
    __shared__ float wAs[32][32], wBs[32][32];   // [k][f]
    int tid = threadIdx.x;
    int r = tid >> 5, lane = tid & 31;
    int nA = blockIdx.x * 16 + r;               // grid exact: NN/16
    int nB = nA + 8;
    int dnA = cnt[nA] + 1, dnB = cnt[nB] + 1;
    int baseA = nA * SLAB, baseB = nB * SLAB;
    int c0A = col[baseA + lane];
    int c0B = col[baseB + lane];
    bool comA = (dnA <= 32), comB = (dnB <= 32);
    int q = lane & 15, sub = lane >> 4;
    unsigned uA[16], uB[16];
    if (comA) {
        #pragma unroll
        for (int s = 0; s < 16; ++s) {
            int c = __shfl(c0A, 2 * s + sub, 32);
            uA[s] = hsp[(size_t)c * 16 + q];
        }
    }
    if (comB) {
        #pragma unroll
        for (int s = 0; s < 16; ++s) {
            int c = __shfl(c0B, 2 * s + sub, 32);
            uB[s] = hsp[(size_t)c * 16 + q];
        }
    }
    for (int i = tid; i < 1024; i += 256) {     // staging hides gather latency
        int k = i >> 5, f = i & 31;
        wAs[k][f] = W1[k * 64 + f];
        wBs[k][f] = W1[k * 64 + 32 + f];
    }
    __syncthreads();
    float accA, accB;
    if (comA) {
        float aLo = 0.f, aHi = 0.f;
        #pragma unroll
        for (int s = 0; s < 16; ++s) { aLo += bf16_lo(uA[s]); aHi += bf16_hi(uA[s]); }
        aLo += __shfl_xor(aLo, 16);
        aHi += __shfl_xor(aHi, 16);
        float vLo = __shfl(aLo, lane >> 1, 32);
        float vHi = __shfl(aHi, lane >> 1, 32);
        accA = (lane & 1) ? vHi : vLo;
    } else {
        accA = gen_sum_hsp(hsp, col, baseA, dnA, lane);
    }
    if (comB) {
        float aLo = 0.f, aHi = 0.f;
        #pragma unroll
        for (int s = 0; s < 16; ++s) { aLo += bf16_lo(uB[s]); aHi += bf16_hi(uB[s]); }
        aLo += __shfl_xor(aLo, 16);
        aHi += __shfl_xor(aHi, 16);
        float vLo = __shfl(aLo, lane >> 1, 32);
        float vHi = __shfl(aHi, lane >> 1, 32);
        accB = (lane & 1) ? vHi : vLo;
    } else {
        accB = gen_sum_hsp(hsp, col, baseB, dnB, lane);
    }
    gat1_epilogue(accA, nA, lane, dinv, gb, bng, bnb, bnm, bnv, wAs, wBs, as_, ad_, gp, als, ald);
    gat1_epilogue(accB, nB, lane, dinv, gb, bng, bnb, bnm, bnv, wAs, wBs, as_, ad_, gp, als, ald);
}

// ---------------- GAT1 aggregate (one-pass softmax, R12 form) + ReLU + fused GCN2 ----------------

__global__ __launch_bounds__(256) void k_gat1_pv(
    const unsigned* __restrict__ gp, const float2* __restrict__ als,
    const float2* __restrict__ ald,
    const int* __restrict__ cnt, const int* __restrict__ col,
    const float* __restrict__ b, const float* __restrict__ W2,
    const float* __restrict__ dinv, unsigned* __restrict__ hs3p) {
    __shared__ float w2s[32][32];               // [k][f]
    int tid = threadIdx.x;
    int r = tid >> 5, lane = tid & 31;
    int n = blockIdx.x * 8 + r;                 // grid exact: N/8
    int dn = cnt[n] + 1;
    int base = n * SLAB;
    int c0 = col[base + lane];
    float2 ad = ald[n];
    for (int i = tid; i < 1024; i += 256) w2s[i >> 5][i & 31] = W2[i];
    float A0, A1, ws0, ws1;
    if (dn <= 32) {
        int q = lane & 7, sub = lane >> 3;
        const uint4* g4 = (const uint4*)gp;
        float aL0 = 0.f, aL1 = 0.f, aL2 = 0.f, aL3 = 0.f;
        float aH0 = 0.f, aH1 = 0.f, aH2 = 0.f, aH3 = 0.f;
        float w0s = 0.f, w1s = 0.f;
        #pragma unroll
        for (int s = 0; s < 8; ++s) {
            int c = __shfl(c0, 4 * s + sub, 32);
            uint4 u = g4[(size_t)c * 8 + q];
            float2 sl = als[c];
            float w0 = __expf(lrelu(sl.x + ad.x));
            float w1 = __expf(lrelu(sl.y + ad.y));
            aL0 += w0 * bf16_lo(u.x); aH0 += w1 * bf16_hi(u.x);
            aL1 += w0 * bf16_lo(u.y); aH1 += w1 * bf16_hi(u.y);
            aL2 += w0 * bf16_lo(u.z); aH2 += w1 * bf16_hi(u.z);
            aL3 += w0 * bf16_lo(u.w); aH3 += w1 * bf16_hi(u.w);
            w0s += w0; w1s += w1;
        }
        aL0 += __shfl_xor(aL0, 8); aL0 += __shfl_xor(aL0, 16);
        aL1 += __shfl_xor(aL1, 8); aL1 += __shfl_xor(aL1, 16);
        aL2 += __shfl_xor(aL2, 8); aL2 += __shfl_xor(aL2, 16);
        aL3 += __shfl_xor(aL3, 8); aL3 += __shfl_xor(aL3, 16);
        aH0 += __shfl_xor(aH0, 8); aH0 += __shfl_xor(aH0, 16);
        aH1 += __shfl_xor(aH1, 8); aH1 += __shfl_xor(aH1, 16);
        aH2 += __shfl_xor(aH2, 8); aH2 += __shfl_xor(aH2, 16);
        aH3 += __shfl_xor(aH3, 8); aH3 += __shfl_xor(aH3, 16);
        w0s += __shfl_xor(w0s, 8); w0s += __shfl_xor(w0s, 16);
        w1s += __shfl_xor(w1s, 8); w1s += __shfl_xor(w1s, 16);
        int p = lane >> 2;
        float l0 = __shfl(aL0, p, 32), l1 = __shfl(aL1, p, 32);
        float l2 = __shfl(aL2, p, 32), l3 = __shfl(aL3, p, 32);
        float h0 = __shfl(aH0, p, 32), h1 = __shfl(aH1, p, 32);
        float h2 = __shfl(aH2, p, 32), h3 = __shfl(aH3, p, 32);
        float sl01 = (lane & 1) ? l1 : l0, sl23 = (lane & 1) ? l3 : l2;
        float sh01 = (lane & 1) ? h1 : h0, sh23 = (lane & 1) ? h3 : h2;
        A0 = (lane & 2) ? sl23 : sl01;
        A1 = (lane & 2) ? sh23 : sh01;
        ws0 = w0s; ws1 = w1s;
    } else {
        int c1 = col[base + 32 + lane];
        int half = lane >> 4, l16 = lane & 15;
        const uint2* gp2 = (const uint2*)gp;
        float a0L = 0.f, a0H = 0.f, a1L = 0.f, a1H = 0.f;
        float w0s = 0.f, w1s = 0.f;
        for (int j2 = 0; j2 < dn; j2 += 4) {
            int eA = j2 + half, eB = j2 + 2 + half;
            int cA = __shfl((j2 < 32) ? c0 : c1, eA & 31, 32);
            int cB = __shfl((j2 + 2 < 32) ? c0 : c1, eB & 31, 32);
            cA = (eA < dn) ? cA : (int)NN;
            cB = (eB < dn) ? cB : (int)NN;
            uint2 uA = gp2[(size_t)cA * 16 + l16];
            uint2 uB = gp2[(size_t)cB * 16 + l16];
            float2 sA = als[cA], sB = als[cB];
            float wA0 = __expf(lrelu(sA.x + ad.x)), wA1 = __expf(lrelu(sA.y + ad.y));
            float wB0 = __expf(lrelu(sB.x + ad.x)), wB1 = __expf(lrelu(sB.y + ad.y));
            a0L += wA0 * bf16_lo(uA.x) + wB0 * bf16_lo(uB.x);
            a1L += wA1 * bf16_hi(uA.x) + wB1 * bf16_hi(uB.x);
            a0H += wA0 * bf16_lo(uA.y) + wB0 * bf16_lo(uB.y);
            a1H += wA1 * bf16_hi(uA.y) + wB1 * bf16_hi(uB.y);
            w0s += wA0 + wB0; w1s += wA1 + wB1;
        }
        a0L += __shfl_xor(a0L, 16); a0H += __shfl_xor(a0H, 16);
        a1L += __shfl_xor(a1L, 16); a1H += __shfl_xor(a1H, 16);
        w0s += __shfl_xor(w0s, 16); w1s += __shfl_xor(w1s, 16);
        int p = lane >> 1;
        float t0L = __shfl(a0L, p, 32), t0H = __shfl(a0H, p, 32);
        float t1L = __shfl(a1L, p, 32), t1H = __shfl(a1H, p, 32);
        A0 = (lane & 1) ? t0H : t0L;
        A1 = (lane & 1) ? t1H : t1L;
        ws0 = w0s; ws1 = w1s;
    }
    __syncthreads();
    float v = 0.5f * (A0 / ws0 + A1 / ws1) + b[lane];
    v = fmaxf(v, 0.f);                           // h2[n][lane]
    float g0 = 0.f, g1 = 0.f;
    #pragma unroll
    for (int k = 0; k < 32; k += 2) {
        g0 += __shfl(v, k, 32) * w2s[k][lane];
        g1 += __shfl(v, k + 1, 32) * w2s[k + 1][lane];
    }
    unsigned r16 = rne_bf16((g0 + g1) * dinv[n]);
    unsigned hi16 = __shfl(r16, lane + 1, 32);
    if (!(lane & 1)) hs3p[n * 16 + (lane >> 1)] = (hi16 << 16) | (r16 & 0xffffu);
}

// ---------------- GCN2 agg (2 nodes/half-wave) + BN + ReLU + fused GAT2 transform ----------------

__global__ __launch_bounds__(256, 4) void k_gcn2_gat2t(
    const unsigned* __restrict__ hsp, const int* __restrict__ cnt,
    const int* __restrict__ col, const float* __restrict__ dinv,
    const float* __restrict__ gb, const float* __restrict__ bng,
    const float* __restrict__ bnb, const float* __restrict__ bnm,
    const float* __restrict__ bnv,
    const float* __restrict__ Wg, const float* __restrict__ as_, const float* __restrict__ ad_,
    unsigned* __restrict__ g2p, float2* __restrict__ als, float2* __restrict__ ald) {
    __shared__ float wgs[32][32];               // [k][o]
    int tid = threadIdx.x;
    int r = tid >> 5, lane = tid & 31;
    int nA = blockIdx.x * 16 + r;               // grid exact: NN/16
    int nB = nA + 8;
    int dnA = cnt[nA] + 1, dnB = cnt[nB] + 1;
    int baseA = nA * SLAB, baseB = nB * SLAB;
    int c0A = col[baseA + lane];
    int c0B = col[baseB + lane];
    bool comA = (dnA <= 32), comB = (dnB <= 32);
    int q = lane & 15, sub = lane >> 4;
    unsigned uA[16], uB[16];
    if (comA) {
        #pragma unroll
        for (int s = 0; s < 16; ++s) {
            int c = __shfl(c0A, 2 * s + sub, 32);
            uA[s] = hsp[(size_t)c * 16 + q];
        }
    }
    if (comB) {
        #pragma unroll
        for (int s = 0; s < 16; ++s) {
            int c = __shfl(c0B, 2 * s + sub, 32);
            uB[s] = hsp[(size_t)c * 16 + q];
        }
    }
    for (int i = tid; i < 1024; i += 256) wgs[i >> 5][i & 31] = Wg[i];
    __syncthreads();
    float accA, accB;
    if (comA) {
        float aLo = 0.f, aHi = 0.f;
        #pragma unroll
        for (int s = 0; s < 16; ++s) { aLo += bf16_lo(uA[s]); aHi += bf16_hi(uA[s]); }
        aLo += __shfl_xor(aLo, 16);
        aHi += __shfl_xor(aHi, 16);
        float vLo = __shfl(aLo, lane >> 1, 32);
        float vHi = __shfl(aHi, lane >> 1, 32);
        accA = (lane & 1) ? vHi : vLo;
    } else {
        accA = gen_sum_hsp(hsp, col, baseA, dnA, lane);
    }
    if (comB) {
        float aLo = 0.f, aHi = 0.f;
        #pragma unroll
        for (int s = 0; s < 16; ++s) { aLo += bf16_lo(uB[s]); aHi += bf16_hi(uB[s]); }
        aLo += __shfl_xor(aLo, 16);
        aHi += __shfl_xor(aHi, 16);
        float vLo = __shfl(aLo, lane >> 1, 32);
        float vHi = __shfl(aHi, lane >> 1, 32);
        accB = (lane & 1) ? vHi : vLo;
    } else {
        accB = gen_sum_hsp(hsp, col, baseB, dnB, lane);
    }
    gat2t_epilogue(accA, nA, lane, dinv, gb, bng, bnb, bnm, bnv, wgs, as_, ad_, g2p, als, ald);
    gat2t_epilogue(accB, nB, lane, dinv, gb, bng, bnb, bnm, bnv, wgs, as_, ad_, g2p, als, ald);
}

// ---------------- GAT2 aggregate (2 nodes/half-wave, one-pass softmax) + mean + log_softmax ----------------

__global__ __launch_bounds__(256, 4) void k_gat2_agg(
    const unsigned* __restrict__ g2p, const float2* __restrict__ als,
    const float2* __restrict__ ald,
    const int* __restrict__ cnt, const int* __restrict__ col,
    const float* __restrict__ b, float* __restrict__ out) {
    int tid = threadIdx.x;
    int r = tid >> 5, lane = tid & 31;
    int nA = blockIdx.x * 16 + r;               // grid exact: NN/16
    int nB = nA + 8;
    int dnA = cnt[nA] + 1, dnB = cnt[nB] + 1;
    int baseA = nA * SLAB, baseB = nB * SLAB;
    int c0A = col[baseA + lane];
    int c0B = col[baseB + lane];
    float2 adA = ald[nA], adB = ald[nB];
    bool comA = (dnA <= 32), comB = (dnB <= 32);
    int q = lane & 7, sub = lane >> 3;
    bool head1 = (lane & 4) != 0;               // q>=4 => feats 16..31 = head 1
    const uint2* g2 = (const uint2*)g2p;
    uint2 uA[8], uB[8];
    if (comA) {
        #pragma unroll
        for (int s = 0; s < 8; ++s) {
            int c = __shfl(c0A, 4 * s + sub, 32);
            uA[s] = g2[(size_t)c * 8 + q];
        }
    }
    if (comB) {
        #pragma unroll
        for (int s = 0; s < 8; ++s) {
            int c = __shfl(c0B, 4 * s + sub, 32);
            uB[s] = g2[(size_t)c * 8 + q];
        }
    }
    float accA, wsA0, wsA1, accB, wsB0, wsB1;
    if (comA) {
        float ac0 = 0.f, ac1 = 0.f, ac2 = 0.f, ac3 = 0.f;
        float w0s = 0.f, w1s = 0.f;
        #pragma unroll
        for (int s = 0; s < 8; ++s) {
            int c = __shfl(c0A, 4 * s + sub, 32);
            float2 sl = als[c];
            float w0 = __expf(lrelu(sl.x + adA.x));
            float w1 = __expf(lrelu(sl.y + adA.y));
            float w = head1 ? w1 : w0;
            ac0 += w * bf16_lo(uA[s].x); ac1 += w * bf16_hi(uA[s].x);
            ac2 += w * bf16_lo(uA[s].y); ac3 += w * bf16_hi(uA[s].y);
            w0s += w0; w1s += w1;
        }
        ac0 += __shfl_xor(ac0, 8); ac0 += __shfl_xor(ac0, 16);
        ac1 += __shfl_xor(ac1, 8); ac1 += __shfl_xor(ac1, 16);
        ac2 += __shfl_xor(ac2, 8); ac2 += __shfl_xor(ac2, 16);
        ac3 += __shfl_xor(ac3, 8); ac3 += __shfl_xor(ac3, 16);
        w0s += __shfl_xor(w0s, 8); w0s += __shfl_xor(w0s, 16);
        w1s += __shfl_xor(w1s, 8); w1s += __shfl_xor(w1s, 16);
        int p = lane >> 2;
        float v0 = __shfl(ac0, p, 32), v1 = __shfl(ac1, p, 32);
        float v2 = __shfl(ac2, p, 32), v3 = __shfl(ac3, p, 32);
        float s01 = (lane & 1) ? v1 : v0;
        float s23 = (lane & 1) ? v3 : v2;
        accA = (lane & 2) ? s23 : s01;
        wsA0 = w0s; wsA1 = w1s;
    } else {
        gat2_gen(g2p, als, adA, col, baseA, dnA, lane, accA, wsA0, wsA1);
    }
    if (comB) {
        float ac0 = 0.f, ac1 = 0.f, ac2 = 0.f, ac3 = 0.f;
        float w0s = 0.f, w1s = 0.f;
        #pragma unroll
        for (int s = 0; s < 8; ++s) {
            int c = __shfl(c0B, 4 * s + sub, 32);
            float2 sl = als[c];
            float w0 = __expf(lrelu(sl.x + adB.x));
            float w1 = __expf(lrelu(sl.y + adB.y));
            float w = head1 ? w1 : w0;
            ac0 += w * bf16_lo(uB[s].x); ac1 += w * bf16_hi(uB[s].x);
            ac2 += w * bf16_lo(uB[s].y); ac3 += w * bf16_hi(uB[s].y);
            w0s += w0; w1s += w1;
        }
        ac0 += __shfl_xor(ac0, 8); ac0 += __shfl_xor(ac0, 16);
        ac1 += __shfl_xor(ac1, 8); ac1 += __shfl_xor(ac1, 16);
        ac2 += __shfl_xor(ac2, 8); ac2 += __shfl_xor(ac2, 16);
        ac3 += __shfl_xor(ac3, 8); ac3 += __shfl_xor(ac3, 16);
        w0s += __shfl_xor(w0s, 8); w0s += __shfl_xor(w0s, 16);
        w1s += __shfl_xor(w1s, 8); w1s += __shfl_xor(w1s, 16);
        int p = lane >> 2;
        float v0 = __shfl(ac0, p, 32), v1 = __shfl(ac1, p, 32);
        float v2 = __shfl(ac2, p, 32), v3 = __shfl(ac3, p, 32);
        float s01 = (lane & 1) ? v1 : v0;
        float s23 = (lane & 1) ? v3 : v2;
        accB = (lane & 2) ? s23 : s01;
        wsB0 = w0s; wsB1 = w1s;
    } else {
        gat2_gen(g2p, als, adB, col, baseB, dnB, lane, accB, wsB0, wsB1);
    }
    gat2_out(accA, wsA0, wsA1, nA, lane, b, out);
    gat2_out(accB, wsB0, wsB1, nB, lane, b, out);
}

// ---------------- launch ----------------

static inline size_t al256(size_t x) { return (x + 255) & ~((size_t)255); }

extern "C" void kernel_launch(void* const* d_in, const int* in_sizes, int n_in,
                              void* d_out, int out_size, void* d_ws, size_t ws_size,
                              hipStream_t stream) {
    const float* x      = (const float*)d_in[0];
    const int*   ei     = (const int*)d_in[1];
    const float* gcn1_W = (const float*)d_in[2];
    const float* gcn1_b = (const float*)d_in[3];
    const float* bn1_g  = (const float*)d_in[4];
    const float* bn1_b  = (const float*)d_in[5];
    const float* bn1_m  = (const float*)d_in[6];
    const float* bn1_v  = (const float*)d_in[7];
    const float* gat1_W = (const float*)d_in[8];
    const float* gat1_as= (const float*)d_in[9];
    const float* gat1_ad= (const float*)d_in[10];
    const float* gat1_b = (const float*)d_in[11];
    const float* gcn2_W = (const float*)d_in[12];
    const float* gcn2_b = (const float*)d_in[13];
    const float* bn2_g  = (const float*)d_in[14];
    const float* bn2_b  = (const float*)d_in[15];
    const float* bn2_m  = (const float*)d_in[16];
    const float* bn2_v  = (const float*)d_in[17];
    const float* gat2_W = (const float*)d_in[18];
    const float* gat2_as= (const float*)d_in[19];
    const float* gat2_ad= (const float*)d_in[20];
    const float* gat2_b = (const float*)d_in[21];
    float* out = (float*)d_out;

    char* w = (char*)d_ws;
    size_t off = 0;
    auto alloc = [&](size_t bytes) { void* p = w + off; off = al256(off + bytes); return p; };
    int*      cnt   = (int*)alloc((size_t)NN * 4);
    float*    dinv  = (float*)alloc((size_t)NN * 4);
    int*      col   = (int*)alloc((size_t)NN * SLAB * 4);
    unsigned* hsp   = (unsigned*)alloc((size_t)(NN + 1) * 16 * 4); // hs1/hs3 (bf16 pairs) + zero row
    unsigned* g1p   = (unsigned*)alloc((size_t)(NN + 1) * 32 * 4); // GAT1 feats + zero row
    unsigned* g2p   = (unsigned*)alloc((size_t)(NN + 1) * 16 * 4); // GAT2 feats + zero row
    float2*   als   = (float2*)alloc((size_t)(NN + 1) * 8);        // src logits + -inf sentinel
    float2*   ald   = (float2*)alloc((size_t)NN * 8);              // dst logits (own node)
    int*      bcnt  = (int*)alloc((size_t)KB * 4);
    unsigned int* ebuf = (unsigned int*)g1p;    // alias: 7.4 MB < 12.8 MB; dead before g1p written

    const int* esrc = ei;
    const int* edst = ei + EE;
    const int GE = (EE + CHUNK - 1) / CHUNK;    // 391

    k_z<<<1, 512, 0, stream>>>(bcnt, hsp, g1p, g2p, als);
    k_scat<<<GE, 256, 0, stream>>>(esrc, edst, bcnt, ebuf);
    k_bucket<<<KB, 256, 0, stream>>>(ebuf, bcnt, col, cnt, dinv);

    k_gemm1<<<(NN + 63) / 64, 256, 0, stream>>>(x, gcn1_W, dinv, hsp);         // hs1 (pairs)
    k_gcn1_gat1t<<<NN / 16, 256, 0, stream>>>(hsp, cnt, col, dinv, gcn1_b,
                                              bn1_g, bn1_b, bn1_m, bn1_v,
                                              gat1_W, gat1_as, gat1_ad, g1p, als, ald);
    k_gat1_pv<<<NN / 8, 256, 0, stream>>>(g1p, als, ald, cnt, col, gat1_b,
                                          gcn2_W, dinv, hsp);                  // hs3 (pairs)
    k_gcn2_gat2t<<<NN / 16, 256, 0, stream>>>(hsp, cnt, col, dinv, gcn2_b,
                                              bn2_g, bn2_b, bn2_m, bn2_v,
                                              gat2_W, gat2_as, gat2_ad, g2p, als, ald);
    k_gat2_agg<<<NN / 16, 256, 0, stream>>>(g2p, als, ald, cnt, col, gat2_b, out);
}

// Round 16
// 264.992 us; speedup vs baseline: 1.0621x; 1.0621x over previous
//
#include <hip/hip_runtime.h>
#include <hip/hip_bf16.h>

#define NN 100000
#define EE 1600000
#define SLAB 64            // fixed slab per node
#define KB 391             // buckets of 256 nodes: (NN+255)>>8
#define CHUNK 4096         // edges per block in scatter
#define BSLAB 4736         // per-bucket edge slab: 4096 mean + 10 sigma

static constexpr float EPSV = 1e-5f;
static constexpr float SLOPE = 0.2f;

__device__ __forceinline__ float lrelu(float v) { return v > 0.f ? v : SLOPE * v; }

__device__ __forceinline__ unsigned rne_bf16(float v) {
    unsigned u = __float_as_uint(v);
    return (u + 0x7fffu + ((u >> 16) & 1u)) >> 16;
}
__device__ __forceinline__ float bf16_lo(unsigned u) { return __uint_as_float(u << 16); }
__device__ __forceinline__ float bf16_hi(unsigned u) { return __uint_as_float(u & 0xffff0000u); }

// ---------------- CSR build (fixed bucket slabs) ----------------

__global__ void k_z(int* __restrict__ bcnt, unsigned* __restrict__ hsp,
                    unsigned* __restrict__ g1p, unsigned* __restrict__ g2p,
                    float2* __restrict__ als) {
    int i = threadIdx.x;
    if (i < KB) bcnt[i] = 0;
    if (i < 16) hsp[(size_t)NN * 16 + i] = 0u;   // sentinel zero rows
    if (i < 32) g1p[(size_t)NN * 32 + i] = 0u;
    if (i < 16) g2p[(size_t)NN * 16 + i] = 0u;
    if (i == 0) als[NN] = make_float2(-1e30f, -1e30f);  // sentinel: w -> 0
}

__global__ __launch_bounds__(256) void k_scat(const int* __restrict__ src, const int* __restrict__ dst,
                                              int* __restrict__ bcnt, unsigned int* __restrict__ ebuf) {
    __shared__ int hc[KB], hb[KB];
    int tid = threadIdx.x;
    for (int i = tid; i < KB; i += 256) hc[i] = 0;
    __syncthreads();
    int e0 = blockIdx.x * CHUNK;
    #pragma unroll
    for (int r = 0; r < CHUNK / 256; ++r) {
        int e = e0 + r * 256 + tid;
        if (e < EE) atomicAdd(&hc[dst[e] >> 8], 1);
    }
    __syncthreads();
    for (int i = tid; i < KB; i += 256) {
        int c = hc[i];
        if (c) hb[i] = atomicAdd(&bcnt[i], c);
        hc[i] = 0;
    }
    __syncthreads();
    #pragma unroll
    for (int r = 0; r < CHUNK / 256; ++r) {
        int e = e0 + r * 256 + tid;
        if (e < EE) {
            int d = dst[e];
            int b = d >> 8;
            int rk = atomicAdd(&hc[b], 1);
            ebuf[(size_t)b * BSLAB + hb[b] + rk] = ((unsigned)src[e] << 8) | (unsigned)(d & 255);
        }
    }
}

// bucket demux + fused deg/dinv/self-loop/sentinel-pad
__global__ __launch_bounds__(256) void k_bucket(const unsigned int* __restrict__ ebuf,
                                                const int* __restrict__ bcnt,
                                                int* __restrict__ col, int* __restrict__ cnt,
                                                float* __restrict__ dinv) {
    __shared__ int lc[256];
    int tid = threadIdx.x;
    int b = blockIdx.x;
    lc[tid] = 0;
    __syncthreads();
    size_t s = (size_t)b * BSLAB;
    int nb = bcnt[b];
    for (int i = tid; i < nb; i += 256) {
        unsigned v = ebuf[s + i];
        int l = v & 255;
        int r = atomicAdd(&lc[l], 1);
        col[(((b << 8) + l) << 6) + r] = v >> 8;
    }
    __syncthreads();
    int node = (b << 8) + tid;
    if (node < NN) {
        int c = lc[tid];
        cnt[node] = c;
        dinv[node] = rsqrtf((float)(c + 1));
        col[node * SLAB + c] = node;                       // self loop
        for (int j = c + 1; j < 32; ++j) col[node * SLAB + j] = NN;  // sentinel pad
    }
}

// ---------------- GEMM1: hs(pairs) = bf16((x @ W) * dinv[n]) ----------------

__global__ __launch_bounds__(256) void k_gemm1(const float* __restrict__ x,
                                               const float* __restrict__ W,
                                               const float* __restrict__ dinv,
                                               unsigned* __restrict__ hsp) {
    __shared__ float xs[64][128];               // 32 KB
    int tid = threadIdx.x;
    int lane = tid & 63;
    int wv = tid >> 6;
    int khalf = lane >> 5, f = lane & 31;
    float wreg[64];
    const float* wp = W + (khalf * 64) * 32 + f;
    #pragma unroll
    for (int i = 0; i < 64; ++i) wreg[i] = wp[i * 32];
    int n0 = blockIdx.x * 64;
    for (int i = tid; i < 64 * 32; i += 256) {
        int row = i >> 5, c4 = i & 31;
        int n = n0 + row;
        float4 v = (n < NN) ? *(const float4*)&x[(size_t)n * 128 + c4 * 4]
                            : make_float4(0.f, 0.f, 0.f, 0.f);
        *(float4*)&xs[row][c4 * 4] = v;
    }
    __syncthreads();
    #pragma unroll 4
    for (int t = 0; t < 16; ++t) {
        int row = wv * 16 + t;
        int n = n0 + row;
        if (n >= NN) break;
        const float* xp = &xs[row][khalf * 64];
        float a0 = 0.f, a1 = 0.f, a2 = 0.f, a3 = 0.f;
        #pragma unroll
        for (int j = 0; j < 16; j += 4) {
            float4 v0 = *(const float4*)&xp[(j + 0) * 4];
            float4 v1 = *(const float4*)&xp[(j + 1) * 4];
            float4 v2 = *(const float4*)&xp[(j + 2) * 4];
            float4 v3 = *(const float4*)&xp[(j + 3) * 4];
            a0 += v0.x * wreg[j * 4 + 0]  + v0.y * wreg[j * 4 + 1]  + v0.z * wreg[j * 4 + 2]  + v0.w * wreg[j * 4 + 3];
            a1 += v1.x * wreg[j * 4 + 4]  + v1.y * wreg[j * 4 + 5]  + v1.z * wreg[j * 4 + 6]  + v1.w * wreg[j * 4 + 7];
            a2 += v2.x * wreg[j * 4 + 8]  + v2.y * wreg[j * 4 + 9]  + v2.z * wreg[j * 4 + 10] + v2.w * wreg[j * 4 + 11];
            a3 += v3.x * wreg[j * 4 + 12] + v3.y * wreg[j * 4 + 13] + v3.z * wreg[j * 4 + 14] + v3.w * wreg[j * 4 + 15];
        }
        float tot = (a0 + a1) + (a2 + a3);
        tot += __shfl_xor(tot, 32);
        unsigned r16 = rne_bf16(tot * dinv[n]);
        unsigned hi16 = __shfl(r16, f + 1, 32);
        if (khalf == 0 && !(f & 1))
            hsp[n * 16 + (f >> 1)] = (hi16 << 16) | (r16 & 0xffffu);
    }
}

// generic (dn>32) masked pair-gather sum -> per-feat acc
__device__ __forceinline__ float gen_sum_hsp(const unsigned* hsp, const int* col, int base,
                                             int dn, int lane) {
    int half = lane >> 4, l16 = lane & 15;
    int c0 = col[base + lane];
    int c1 = col[base + 32 + lane];
    float aL0 = 0.f, aH0 = 0.f, aL1 = 0.f, aH1 = 0.f;
    for (int j2 = 0; j2 < dn; j2 += 4) {
        int eA = j2 + half, eB = j2 + 2 + half;
        int cA = __shfl((j2 < 32) ? c0 : c1, eA & 31, 32);
        int cB = __shfl((j2 + 2 < 32) ? c0 : c1, eB & 31, 32);
        cA = (eA < dn) ? cA : (int)NN;
        cB = (eB < dn) ? cB : (int)NN;
        unsigned uA = hsp[(size_t)cA * 16 + l16];
        unsigned uB = hsp[(size_t)cB * 16 + l16];
        aL0 += bf16_lo(uA); aH0 += bf16_hi(uA);
        aL1 += bf16_lo(uB); aH1 += bf16_hi(uB);
    }
    float accLo = aL0 + aL1, accHi = aH0 + aH1;
    accLo += __shfl_xor(accLo, 16);
    accHi += __shfl_xor(accHi, 16);
    float vLo = __shfl(accLo, lane >> 1, 32);
    float vHi = __shfl(accHi, lane >> 1, 32);
    return (lane & 1) ? vHi : vLo;
}

// ---------------- GCN1 agg (8 x uint2 gather) + BN + ReLU + fused GAT1 transform ----------------

__global__ __launch_bounds__(256, 4) void k_gcn1_gat1t(
    const unsigned* __restrict__ hsp, const int* __restrict__ cnt,
    const int* __restrict__ col, const float* __restrict__ dinv,
    const float* __restrict__ gb, const float* __restrict__ bng,
    const float* __restrict__ bnb, const float* __restrict__ bnm,
    const float* __restrict__ bnv,
    const float* __restrict__ W1, const float* __restrict__ as_, const float* __restrict__ ad_,
    unsigned* __restrict__ gp, float2* __restrict__ als, float2* __restrict__ ald) {
    __shared__ float wAs[32][32], wBs[32][32];   // [k][f]
    int tid = threadIdx.x;
    int r = tid >> 5, lane = tid & 31;
    int n = blockIdx.x * 8 + r;                 // grid exact: N/8
    int dn = cnt[n] + 1;
    int base = n * SLAB;
    int c0 = col[base + lane];
    bool common = (dn <= 32);
    // 8-lane/row uint2 gather: 8 loads/lane, 16 regs state, half the VMEM instrs of 16x uint
    uint2 u[8];
    int q = lane & 7, g = lane >> 3;            // q = uint2 index in row, g = edge group 0..3
    if (common) {
        const uint2* h2 = (const uint2*)hsp;
        #pragma unroll
        for (int s = 0; s < 8; ++s) {
            int c = __shfl(c0, s * 4 + g, 32);
            u[s] = h2[(size_t)c * 8 + q];
        }
    }
    for (int i = tid; i < 1024; i += 256) {     // staging hides gather latency
        int k = i >> 5, f = i & 31;
        wAs[k][f] = W1[k * 64 + f];
        wBs[k][f] = W1[k * 64 + 32 + f];
    }
    __syncthreads();
    float acc;
    if (common) {
        float a0 = 0.f, a1 = 0.f, a2 = 0.f, a3 = 0.f;   // feats 4q+0..3
        #pragma unroll
        for (int s = 0; s < 8; ++s) {
            a0 += bf16_lo(u[s].x); a1 += bf16_hi(u[s].x);
            a2 += bf16_lo(u[s].y); a3 += bf16_hi(u[s].y);
        }
        a0 += __shfl_xor(a0, 8); a0 += __shfl_xor(a0, 16);
        a1 += __shfl_xor(a1, 8); a1 += __shfl_xor(a1, 16);
        a2 += __shfl_xor(a2, 8); a2 += __shfl_xor(a2, 16);
        a3 += __shfl_xor(a3, 8); a3 += __shfl_xor(a3, 16);
        int p = lane >> 2;                      // src lane holds q = p
        float t0 = __shfl(a0, p, 32);
        float t1 = __shfl(a1, p, 32);
        float t2 = __shfl(a2, p, 32);
        float t3 = __shfl(a3, p, 32);
        float s01 = (lane & 1) ? t1 : t0;
        float s23 = (lane & 1) ? t3 : t2;
        acc = (lane & 2) ? s23 : s01;
    } else {
        acc = gen_sum_hsp(hsp, col, base, dn, lane);
    }
    float v = dinv[n] * acc + gb[lane];
    v = (v - bnm[lane]) * rsqrtf(bnv[lane] + EPSV) * bng[lane] + bnb[lane];
    v = fmaxf(v, 0.f);                           // t1[n][lane]
    float gA0 = 0.f, gA1 = 0.f, gB0 = 0.f, gB1 = 0.f;
    #pragma unroll
    for (int k = 0; k < 32; k += 2) {
        float t0 = __shfl(v, k, 32);
        float t1v = __shfl(v, k + 1, 32);
        gA0 += t0 * wAs[k][lane];     gB0 += t0 * wBs[k][lane];
        gA1 += t1v * wAs[k + 1][lane]; gB1 += t1v * wBs[k + 1][lane];
    }
    float gA = gA0 + gA1, gB = gB0 + gB1;
    float pas0 = gA * as_[lane],      pad0 = gA * ad_[lane];
    float pas1 = gB * as_[32 + lane], pad1 = gB * ad_[32 + lane];
    #pragma unroll
    for (int off = 16; off; off >>= 1) {
        pas0 += __shfl_xor(pas0, off);
        pad0 += __shfl_xor(pad0, off);
        pas1 += __shfl_xor(pas1, off);
        pad1 += __shfl_xor(pad1, off);
    }
    if (lane == 0) { als[n] = make_float2(pas0, pas1); ald[n] = make_float2(pad0, pad1); }
    gp[n * 32 + lane] = (rne_bf16(gB) << 16) | rne_bf16(gA);
}

// ---------------- GAT1 aggregate (one-pass softmax, R12 form) + ReLU + fused GCN2 ----------------

__global__ __launch_bounds__(256) void k_gat1_pv(
    const unsigned* __restrict__ gp, const float2* __restrict__ als,
    const float2* __restrict__ ald,
    const int* __restrict__ cnt, const int* __restrict__ col,
    const float* __restrict__ b, const float* __restrict__ W2,
    const float* __restrict__ dinv, unsigned* __restrict__ hs3p) {
    __shared__ float w2s[32][32];               // [k][f]
    int tid = threadIdx.x;
    int r = tid >> 5, lane = tid & 31;
    int n = blockIdx.x * 8 + r;                 // grid exact: N/8
    int dn = cnt[n] + 1;
    int base = n * SLAB;
    int c0 = col[base + lane];
    float2 ad = ald[n];
    for (int i = tid; i < 1024; i += 256) w2s[i >> 5][i & 31] = W2[i];
    float A0, A1, ws0, ws1;
    if (dn <= 32) {
        int q = lane & 7, sub = lane >> 3;
        const uint4* g4 = (const uint4*)gp;
        float aL0 = 0.f, aL1 = 0.f, aL2 = 0.f, aL3 = 0.f;
        float aH0 = 0.f, aH1 = 0.f, aH2 = 0.f, aH3 = 0.f;
        float w0s = 0.f, w1s = 0.f;
        #pragma unroll
        for (int s = 0; s < 8; ++s) {
            int c = __shfl(c0, 4 * s + sub, 32);
            uint4 u = g4[(size_t)c * 8 + q];
            float2 sl = als[c];
            float w0 = __expf(lrelu(sl.x + ad.x));
            float w1 = __expf(lrelu(sl.y + ad.y));
            aL0 += w0 * bf16_lo(u.x); aH0 += w1 * bf16_hi(u.x);
            aL1 += w0 * bf16_lo(u.y); aH1 += w1 * bf16_hi(u.y);
            aL2 += w0 * bf16_lo(u.z); aH2 += w1 * bf16_hi(u.z);
            aL3 += w0 * bf16_lo(u.w); aH3 += w1 * bf16_hi(u.w);
            w0s += w0; w1s += w1;
        }
        aL0 += __shfl_xor(aL0, 8); aL0 += __shfl_xor(aL0, 16);
        aL1 += __shfl_xor(aL1, 8); aL1 += __shfl_xor(aL1, 16);
        aL2 += __shfl_xor(aL2, 8); aL2 += __shfl_xor(aL2, 16);
        aL3 += __shfl_xor(aL3, 8); aL3 += __shfl_xor(aL3, 16);
        aH0 += __shfl_xor(aH0, 8); aH0 += __shfl_xor(aH0, 16);
        aH1 += __shfl_xor(aH1, 8); aH1 += __shfl_xor(aH1, 16);
        aH2 += __shfl_xor(aH2, 8); aH2 += __shfl_xor(aH2, 16);
        aH3 += __shfl_xor(aH3, 8); aH3 += __shfl_xor(aH3, 16);
        w0s += __shfl_xor(w0s, 8); w0s += __shfl_xor(w0s, 16);
        w1s += __shfl_xor(w1s, 8); w1s += __shfl_xor(w1s, 16);
        int p = lane >> 2;
        float l0 = __shfl(aL0, p, 32), l1 = __shfl(aL1, p, 32);
        float l2 = __shfl(aL2, p, 32), l3 = __shfl(aL3, p, 32);
        float h0 = __shfl(aH0, p, 32), h1 = __shfl(aH1, p, 32);
        float h2 = __shfl(aH2, p, 32), h3 = __shfl(aH3, p, 32);
        float sl01 = (lane & 1) ? l1 : l0, sl23 = (lane & 1) ? l3 : l2;
        float sh01 = (lane & 1) ? h1 : h0, sh23 = (lane & 1) ? h3 : h2;
        A0 = (lane & 2) ? sl23 : sl01;
        A1 = (lane & 2) ? sh23 : sh01;
        ws0 = w0s; ws1 = w1s;
    } else {
        int c1 = col[base + 32 + lane];
        int half = lane >> 4, l16 = lane & 15;
        const uint2* gp2 = (const uint2*)gp;
        float a0L = 0.f, a0H = 0.f, a1L = 0.f, a1H = 0.f;
        float w0s = 0.f, w1s = 0.f;
        for (int j2 = 0; j2 < dn; j2 += 4) {
            int eA = j2 + half, eB = j2 + 2 + half;
            int cA = __shfl((j2 < 32) ? c0 : c1, eA & 31, 32);
            int cB = __shfl((j2 + 2 < 32) ? c0 : c1, eB & 31, 32);
            cA = (eA < dn) ? cA : (int)NN;
            cB = (eB < dn) ? cB : (int)NN;
            uint2 uA = gp2[(size_t)cA * 16 + l16];
            uint2 uB = gp2[(size_t)cB * 16 + l16];
            float2 sA = als[cA], sB = als[cB];
            float wA0 = __expf(lrelu(sA.x + ad.x)), wA1 = __expf(lrelu(sA.y + ad.y));
            float wB0 = __expf(lrelu(sB.x + ad.x)), wB1 = __expf(lrelu(sB.y + ad.y));
            a0L += wA0 * bf16_lo(uA.x) + wB0 * bf16_lo(uB.x);
            a1L += wA1 * bf16_hi(uA.x) + wB1 * bf16_hi(uB.x);
            a0H += wA0 * bf16_lo(uA.y) + wB0 * bf16_lo(uB.y);
            a1H += wA1 * bf16_hi(uA.y) + wB1 * bf16_hi(uB.y);
            w0s += wA0 + wB0; w1s += wA1 + wB1;
        }
        a0L += __shfl_xor(a0L, 16); a0H += __shfl_xor(a0H, 16);
        a1L += __shfl_xor(a1L, 16); a1H += __shfl_xor(a1H, 16);
        w0s += __shfl_xor(w0s, 16); w1s += __shfl_xor(w1s, 16);
        int p = lane >> 1;
        float t0L = __shfl(a0L, p, 32), t0H = __shfl(a0H, p, 32);
        float t1L = __shfl(a1L, p, 32), t1H = __shfl(a1H, p, 32);
        A0 = (lane & 1) ? t0H : t0L;
        A1 = (lane & 1) ? t1H : t1L;
        ws0 = w0s; ws1 = w1s;
    }
    __syncthreads();
    float v = 0.5f * (A0 / ws0 + A1 / ws1) + b[lane];
    v = fmaxf(v, 0.f);                           // h2[n][lane]
    float g0 = 0.f, g1 = 0.f;
    #pragma unroll
    for (int k = 0; k < 32; k += 2) {
        g0 += __shfl(v, k, 32) * w2s[k][lane];
        g1 += __shfl(v, k + 1, 32) * w2s[k + 1][lane];
    }
    unsigned r16 = rne_bf16((g0 + g1) * dinv[n]);
    unsigned hi16 = __shfl(r16, lane + 1, 32);
    if (!(lane & 1)) hs3p[n * 16 + (lane >> 1)] = (hi16 << 16) | (r16 & 0xffffu);
}

// ---------------- GCN2 agg (8 x uint2 gather) + BN + ReLU + fused GAT2 transform ----------------

__global__ __launch_bounds__(256, 4) void k_gcn2_gat2t(
    const unsigned* __restrict__ hsp, const int* __restrict__ cnt,
    const int* __restrict__ col, const float* __restrict__ dinv,
    const float* __restrict__ gb, const float* __restrict__ bng,
    const float* __restrict__ bnb, const float* __restrict__ bnm,
    const float* __restrict__ bnv,
    const float* __restrict__ Wg, const float* __restrict__ as_, const float* __restrict__ ad_,
    unsigned* __restrict__ g2p, float2* __restrict__ als, float2* __restrict__ ald) {
    __shared__ float wgs[32][32];               // [k][o]
    int tid = threadIdx.x;
    int r = tid >> 5, lane = tid & 31;
    int n = blockIdx.x * 8 + r;                 // grid exact
    int dn = cnt[n] + 1;
    int base = n * SLAB;
    int c0 = col[base + lane];
    bool common = (dn <= 32);
    uint2 u[8];
    int q = lane & 7, g = lane >> 3;
    if (common) {
        const uint2* h2 = (const uint2*)hsp;
        #pragma unroll
        for (int s = 0; s < 8; ++s) {
            int c = __shfl(c0, s * 4 + g, 32);
            u[s] = h2[(size_t)c * 8 + q];
        }
    }
    for (int i = tid; i < 1024; i += 256) wgs[i >> 5][i & 31] = Wg[i];
    __syncthreads();
    float acc;
    if (common) {
        float a0 = 0.f, a1 = 0.f, a2 = 0.f, a3 = 0.f;
        #pragma unroll
        for (int s = 0; s < 8; ++s) {
            a0 += bf16_lo(u[s].x); a1 += bf16_hi(u[s].x);
            a2 += bf16_lo(u[s].y); a3 += bf16_hi(u[s].y);
        }
        a0 += __shfl_xor(a0, 8); a0 += __shfl_xor(a0, 16);
        a1 += __shfl_xor(a1, 8); a1 += __shfl_xor(a1, 16);
        a2 += __shfl_xor(a2, 8); a2 += __shfl_xor(a2, 16);
        a3 += __shfl_xor(a3, 8); a3 += __shfl_xor(a3, 16);
        int p = lane >> 2;
        float t0 = __shfl(a0, p, 32);
        float t1 = __shfl(a1, p, 32);
        float t2 = __shfl(a2, p, 32);
        float t3 = __shfl(a3, p, 32);
        float s01 = (lane & 1) ? t1 : t0;
        float s23 = (lane & 1) ? t3 : t2;
        acc = (lane & 2) ? s23 : s01;
    } else {
        acc = gen_sum_hsp(hsp, col, base, dn, lane);
    }
    float v = dinv[n] * acc + gb[lane];
    v = (v - bnm[lane]) * rsqrtf(bnv[lane] + EPSV) * bng[lane] + bnb[lane];
    v = fmaxf(v, 0.f);                           // t2[n][lane]
    float g0 = 0.f, g1 = 0.f;
    #pragma unroll
    for (int k = 0; k < 32; k += 2) {
        g0 += __shfl(v, k, 32) * wgs[k][lane];
        g1 += __shfl(v, k + 1, 32) * wgs[k + 1][lane];
    }
    float gg = g0 + g1;
    int hh = lane >> 4, ff = lane & 15;
    float as_v = gg * as_[hh * 16 + ff];
    float ad_v = gg * ad_[hh * 16 + ff];
    #pragma unroll
    for (int off = 8; off; off >>= 1) {
        as_v += __shfl_xor(as_v, off);
        ad_v += __shfl_xor(ad_v, off);
    }
    float s1v = __shfl(as_v, 16, 32);
    float d1v = __shfl(ad_v, 16, 32);
    if (lane == 0) {
        als[n] = make_float2(as_v, s1v);
        ald[n] = make_float2(ad_v, d1v);
    }
    unsigned r16 = rne_bf16(gg);
    unsigned hi16 = __shfl(r16, lane + 1, 32);
    if (!(lane & 1)) g2p[n * 16 + (lane >> 1)] = (hi16 << 16) | (r16 & 0xffffu);
}

// ---------------- GAT2 aggregate (one-pass softmax, R12 form) + mean + log_softmax ----------------

__global__ __launch_bounds__(256) void k_gat2_agg(
    const unsigned* __restrict__ g2p, const float2* __restrict__ als,
    const float2* __restrict__ ald,
    const int* __restrict__ cnt, const int* __restrict__ col,
    const float* __restrict__ b, float* __restrict__ out) {
    int tid = threadIdx.x;
    int r = tid >> 5, lane = tid & 31;
    int n = blockIdx.x * 8 + r;                 // grid exact
    int dn = cnt[n] + 1;
    int base = n * SLAB;
    int c0 = col[base + lane];
    float2 ad = ald[n];
    float acc, ws0, ws1;
    if (dn <= 32) {
        int q = lane & 7, sub = lane >> 3;
        bool head1 = (lane & 4) != 0;           // q>=4 => feats 16..31 = head 1
        const uint2* g2 = (const uint2*)g2p;
        float ac0 = 0.f, ac1 = 0.f, ac2 = 0.f, ac3 = 0.f;
        float w0s = 0.f, w1s = 0.f;
        #pragma unroll
        for (int s = 0; s < 8; ++s) {
            int c = __shfl(c0, 4 * s + sub, 32);
            uint2 u = g2[(size_t)c * 8 + q];
            float2 sl = als[c];
            float w0 = __expf(lrelu(sl.x + ad.x));
            float w1 = __expf(lrelu(sl.y + ad.y));
            float w = head1 ? w1 : w0;
            ac0 += w * bf16_lo(u.x); ac1 += w * bf16_hi(u.x);
            ac2 += w * bf16_lo(u.y); ac3 += w * bf16_hi(u.y);
            w0s += w0; w1s += w1;
        }
        ac0 += __shfl_xor(ac0, 8); ac0 += __shfl_xor(ac0, 16);
        ac1 += __shfl_xor(ac1, 8); ac1 += __shfl_xor(ac1, 16);
        ac2 += __shfl_xor(ac2, 8); ac2 += __shfl_xor(ac2, 16);
        ac3 += __shfl_xor(ac3, 8); ac3 += __shfl_xor(ac3, 16);
        w0s += __shfl_xor(w0s, 8); w0s += __shfl_xor(w0s, 16);
        w1s += __shfl_xor(w1s, 8); w1s += __shfl_xor(w1s, 16);
        int p = lane >> 2;
        float v0 = __shfl(ac0, p, 32), v1 = __shfl(ac1, p, 32);
        float v2 = __shfl(ac2, p, 32), v3 = __shfl(ac3, p, 32);
        float s01 = (lane & 1) ? v1 : v0;
        float s23 = (lane & 1) ? v3 : v2;
        acc = (lane & 2) ? s23 : s01;
        ws0 = w0s; ws1 = w1s;
    } else {
        int c1 = col[base + 32 + lane];
        int half = lane >> 4, l16 = lane & 15;
        bool head1g = (l16 & 8) != 0;
        float aL0 = 0.f, aH0 = 0.f, aL1 = 0.f, aH1 = 0.f;
        float w0s = 0.f, w1s = 0.f;
        for (int j2 = 0; j2 < dn; j2 += 4) {
            int eA = j2 + half, eB = j2 + 2 + half;
            int cA = __shfl((j2 < 32) ? c0 : c1, eA & 31, 32);
            int cB = __shfl((j2 + 2 < 32) ? c0 : c1, eB & 31, 32);
            cA = (eA < dn) ? cA : (int)NN;
            cB = (eB < dn) ? cB : (int)NN;
            unsigned uA = g2p[(size_t)cA * 16 + l16];
            unsigned uB = g2p[(size_t)cB * 16 + l16];
            float2 sA = als[cA], sB = als[cB];
            float wA0 = __expf(lrelu(sA.x + ad.x)), wA1 = __expf(lrelu(sA.y + ad.y));
            float wB0 = __expf(lrelu(sB.x + ad.x)), wB1 = __expf(lrelu(sB.y + ad.y));
            float wa = head1g ? wA1 : wA0;
            float wb = head1g ? wB1 : wB0;
            aL0 += wa * bf16_lo(uA); aH0 += wa * bf16_hi(uA);
            aL1 += wb * bf16_lo(uB); aH1 += wb * bf16_hi(uB);
            w0s += wA0 + wB0; w1s += wA1 + wB1;
        }
        float accLo = aL0 + aL1, accHi = aH0 + aH1;
        accLo += __shfl_xor(accLo, 16);
        accHi += __shfl_xor(accHi, 16);
        w0s += __shfl_xor(w0s, 16);
        w1s += __shfl_xor(w1s, 16);
        float vLo = __shfl(accLo, lane >> 1, 32);
        float vHi = __shfl(accHi, lane >> 1, 32);
        acc = (lane & 1) ? vHi : vLo;
        ws0 = w0s; ws1 = w1s;
    }
    int hh = lane >> 4, ff = lane & 15;
    acc /= (hh ? ws1 : ws0);
    float v = 0.5f * (acc + __shfl_xor(acc, 16)) + b[ff];
    float mx = v;
    #pragma unroll
    for (int off = 8; off; off >>= 1) mx = fmaxf(mx, __shfl_xor(mx, off));
    float se = __expf(v - mx);
    #pragma unroll
    for (int off = 8; off; off >>= 1) se += __shfl_xor(se, off);
    if (hh == 0) out[(size_t)n * 16 + ff] = v - mx - __logf(se);
}

// ---------------- launch ----------------

static inline size_t al256(size_t x) { return (x + 255) & ~((size_t)255); }

extern "C" void kernel_launch(void* const* d_in, const int* in_sizes, int n_in,
                              void* d_out, int out_size, void* d_ws, size_t ws_size,
                              hipStream_t stream) {
    const float* x      = (const float*)d_in[0];
    const int*   ei     = (const int*)d_in[1];
    const float* gcn1_W = (const float*)d_in[2];
    const float* gcn1_b = (const float*)d_in[3];
    const float* bn1_g  = (const float*)d_in[4];
    const float* bn1_b  = (const float*)d_in[5];
    const float* bn1_m  = (const float*)d_in[6];
    const float* bn1_v  = (const float*)d_in[7];
    const float* gat1_W = (const float*)d_in[8];
    const float* gat1_as= (const float*)d_in[9];
    const float* gat1_ad= (const float*)d_in[10];
    const float* gat1_b = (const float*)d_in[11];
    const float* gcn2_W = (const float*)d_in[12];
    const float* gcn2_b = (const float*)d_in[13];
    const float* bn2_g  = (const float*)d_in[14];
    const float* bn2_b  = (const float*)d_in[15];
    const float* bn2_m  = (const float*)d_in[16];
    const float* bn2_v  = (const float*)d_in[17];
    const float* gat2_W = (const float*)d_in[18];
    const float* gat2_as= (const float*)d_in[19];
    const float* gat2_ad= (const float*)d_in[20];
    const float* gat2_b = (const float*)d_in[21];
    float* out = (float*)d_out;

    char* w = (char*)d_ws;
    size_t off = 0;
    auto alloc = [&](size_t bytes) { void* p = w + off; off = al256(off + bytes); return p; };
    int*      cnt   = (int*)alloc((size_t)NN * 4);
    float*    dinv  = (float*)alloc((size_t)NN * 4);
    int*      col   = (int*)alloc((size_t)NN * SLAB * 4);
    unsigned* hsp   = (unsigned*)alloc((size_t)(NN + 1) * 16 * 4); // hs1/hs3 (bf16 pairs) + zero row
    unsigned* g1p   = (unsigned*)alloc((size_t)(NN + 1) * 32 * 4); // GAT1 feats + zero row
    unsigned* g2p   = (unsigned*)alloc((size_t)(NN + 1) * 16 * 4); // GAT2 feats + zero row
    float2*   als   = (float2*)alloc((size_t)(NN + 1) * 8);        // src logits + -inf sentinel
    float2*   ald   = (float2*)alloc((size_t)NN * 8);              // dst logits (own node)
    int*      bcnt  = (int*)alloc((size_t)KB * 4);
    unsigned int* ebuf = (unsigned int*)g1p;    // alias: 7.4 MB < 12.8 MB; dead before g1p written

    const int* esrc = ei;
    const int* edst = ei + EE;
    const int GE = (EE + CHUNK - 1) / CHUNK;    // 391

    k_z<<<1, 512, 0, stream>>>(bcnt, hsp, g1p, g2p, als);
    k_scat<<<GE, 256, 0, stream>>>(esrc, edst, bcnt, ebuf);
    k_bucket<<<KB, 256, 0, stream>>>(ebuf, bcnt, col, cnt, dinv);

    k_gemm1<<<(NN + 63) / 64, 256, 0, stream>>>(x, gcn1_W, dinv, hsp);         // hs1 (pairs)
    k_gcn1_gat1t<<<NN / 8, 256, 0, stream>>>(hsp, cnt, col, dinv, gcn1_b,
                                             bn1_g, bn1_b, bn1_m, bn1_v,
                                             gat1_W, gat1_as, gat1_ad, g1p, als, ald);
    k_gat1_pv<<<NN / 8, 256, 0, stream>>>(g1p, als, ald, cnt, col, gat1_b,
                                          gcn2_W, dinv, hsp);                  // hs3 (pairs)
    k_gcn2_gat2t<<<NN / 8, 256, 0, stream>>>(hsp, cnt, col, dinv, gcn2_b,
                                             bn2_g, bn2_b, bn2_m, bn2_v,
                                             gat2_W, gat2_as, gat2_ad, g2p, als, ald);
    k_gat2_agg<<<NN / 8, 256, 0, stream>>>(g2p, als, ald, cnt, col, gat2_b, out);
}